// Round 20
// baseline (861.957 us; speedup 1.0000x reference)
//
#include <hip/hip_runtime.h>
#include <hip/hip_fp16.h>

#define LDIM 50
#define MBIN 262144
#define ODIM 155
#define VOCABSZ 100

typedef _Float16 f16x4 __attribute__((ext_vector_type(4)));
typedef _Float16 f16x2 __attribute__((ext_vector_type(2)));
typedef float    f32x4 __attribute__((ext_vector_type(4)));

// packed fp16 relu: v_pk_max_f16 with 0 (ROCm 7.2 header lacks __hmax2)
static __device__ __forceinline__ __half2 relu2(__half2 a) {
    f16x2 av; __builtin_memcpy(&av, &a, sizeof(av));
    const f16x2 zv = {(_Float16)0.0f, (_Float16)0.0f};
    f16x2 r = __builtin_elementwise_max(av, zv);
    __half2 out; __builtin_memcpy(&out, &r, sizeof(out));
    return out;
}

// ---- workspace half-offsets (from (__half*)ws) ----
#define H_TBL  0       // 800*56 halves padded gather tables (T|pe|ve)
#define H_TO   44800   // [100][50] half2 pairs {Tb, oe}
#define H_WC   54800   // WtCat  [64][116]  (232B rows, rows k>=100 ZERO)
#define H_WU   62224   // W_unT  [64][68]   (136B rows)
#define H_WV   66576   // W_univT[64][68]
#define H_WF   70928   // W_finT [160][68]  (ends 81808)
#define H_WATT 81808   // 28 half2 padded W_att
#define F_LG   40960   // float-offset: 300 attention logits fp32

// H scratch row layout (first 232B of each out row j, written by pred_build):
//   halves [0..50)=hA, [50..100)=hB, [100]=w0, [101]=w2, [102]=w1,
//   [103]=(half)op, [104..116)=0.  GEMM1's Wcat rows 100..103 are zero, so
//   the scalar pad contributes nothing to lin2.
#define OUTROW_B 620    // bytes per out row (155 f32)

// ---- kernel B LDS: per-wave slab [16][232B]; 2 waves/block ----
#define LB_WAVE 3712
#define LDS_BYTES (2*LB_WAVE)   // 7424 B

// ---------------------------------------------------------------------------
// Precompute: identical to round 18/19 (proven)
// ---------------------------------------------------------------------------
__global__ __launch_bounds__(256) void precompute_kernel(
    const float* __restrict__ pe, const float* __restrict__ ve, const float* __restrict__ oe,
    const float* __restrict__ W_pred, const float* __restrict__ b_pred,
    const float* __restrict__ W_bin, const float* __restrict__ b_bin,
    const float* __restrict__ W_un, const float* __restrict__ W_univ,
    const float* __restrict__ W_fin,
    const float* __restrict__ W_att, const float* __restrict__ b_att,
    float* __restrict__ ws)
{
    __half* wsh = (__half*)ws;
    const int bid = blockIdx.x, tid = threadIdx.x;
    if (bid < 150) {
        const int row = bid*4 + (tid >> 6);
        const int t = tid & 63;
        const int s = row / VOCABSZ, v = row % VOCABSZ;
        if (t < 56) {
            float acc = 0.0f;
            if (t < 50) {
                acc = (s == 0) ? b_pred[t] : 0.0f;
                const float* E = (s == 0) ? pe : ve;
#pragma unroll
                for (int e = 0; e < 50; ++e)
                    acc += E[v*50 + e] * W_pred[(s*50 + e)*50 + t];
            }
            wsh[H_TBL + row*56 + t] = __float2half_rn(acc);
        }
    } else if (bid < 152) {
        const int which = bid - 150;
        const float* E = which ? ve : pe;
        const int base = H_TBL + (600 + which*100) * 56;
        for (int idx = tid; idx < 5600; idx += 256) {
            const int r = idx / 56, c = idx % 56;
            wsh[base + idx] = __float2half_rn((c < 50) ? E[r*50 + c] : 0.0f);
        }
    } else if (bid < 177) {
        const int v = (bid - 152)*4 + (tid >> 6);
        const int t = tid & 63;
        if (t < 50) {
            float acc = b_bin[t];
#pragma unroll
            for (int e = 0; e < 50; ++e)
                acc += oe[v*50 + e] * W_bin[(50 + e)*50 + t];
            wsh[H_TO + (v*50 + t)*2]     = __float2half_rn(acc);
            wsh[H_TO + (v*50 + t)*2 + 1] = __float2half_rn(oe[v*50 + t]);
        }
    } else if (bid == 177) {
        const int n = tid & 63, kc = tid >> 6;
        for (int k = kc*29; k < kc*29 + 29; ++k) {
            float val = 0.0f;
            if (n < 50) {
                if (k < 50)       val = W_bin[k*50 + n];
                else if (k < 100) val = W_bin[(100 + k - 50)*50 + n];
            }
            wsh[H_WC + n*116 + k] = __float2half_rn(val);
        }
    } else if (bid == 178) {
        const int n = tid & 63;
        const int half = tid >> 7;
        const int kc = (tid >> 6) & 1;
        const float* W = half ? W_univ : W_un;
        const int base = half ? H_WV : H_WU;
        for (int k = kc*34; k < kc*34 + 34; ++k) {
            float val = (n < 50 && k < 50) ? W[k*50 + n] : 0.0f;
            wsh[base + n*68 + k] = __float2half_rn(val);
        }
    } else if (bid == 179) {
        for (int idx = tid; idx < 10880; idx += 256) {
            const int n = idx % 160, k = idx / 160;
            float val = (n < ODIM && k < 50) ? W_fin[k*ODIM + n] : 0.0f;
            wsh[H_WF + n*68 + k] = __float2half_rn(val);
        }
    } else {                                // bid == 180: logits fp32 + watt half2
        for (int g = tid; g < 300; g += 256) {
            const int which = g / VOCABSZ, v = g % VOCABSZ;
            const float* E = (which == 0) ? pe : ((which == 1) ? ve : oe);
            float acc = b_att[0];
#pragma unroll
            for (int e = 0; e < 50; ++e)
                acc += E[v*50 + e] * W_att[e];
            ws[F_LG + g] = acc;
        }
        if (tid < 28) {
            const float x = (2*tid < 50)   ? W_att[2*tid]   : 0.0f;
            const float y = (2*tid+1 < 50) ? W_att[2*tid+1] : 0.0f;
            ((__half2*)(wsh + H_WATT))[tid] = __floats2half2_rn(x, y);
        }
    }
}

// ---------------------------------------------------------------------------
// Build one predicate node — packed fp16 from GLOBAL tables (r15 proven)
// ---------------------------------------------------------------------------
__device__ __forceinline__ float build_node(
    int p, const int* __restrict__ v, __half2 e02, const __half2* __restrict__ ek2,
    __half2 invs, const uint4* __restrict__ tq, const __half2* __restrict__ wattl,
    __half2* __restrict__ h2out)
{
    const __half2 z2 = __floats2half2_rn(0.0f, 0.0f);
    __half2 lacc = z2;
#pragma unroll
    for (int g = 0; g < 7; ++g) {
        uint4 ul = tq[p*7 + g];
        uint4 up = tq[(600 + p)*7 + g];
        __half2 lin[4], num[4];
#pragma unroll
        for (int k = 0; k < 4; ++k) {
            lin[k] = ((const __half2*)&ul)[k];
            num[k] = __hmul2(e02, ((const __half2*)&up)[k]);
        }
#pragma unroll
        for (int s = 0; s < 5; ++s) {
            uint4 ua = tq[((s+1)*VOCABSZ + v[s])*7 + g];
            uint4 uv = tq[(700 + v[s])*7 + g];
#pragma unroll
            for (int k = 0; k < 4; ++k) {
                lin[k] = __hadd2(lin[k], ((const __half2*)&ua)[k]);
                num[k] = __hfma2(ek2[s], ((const __half2*)&uv)[k], num[k]);
            }
        }
#pragma unroll
        for (int k = 0; k < 4; ++k) {
            const __half2 h = __hfma2(num[k], invs, relu2(lin[k]));
            h2out[g*4 + k] = h;
            lacc = __hfma2(h, wattl[g*4 + k], lacc);
        }
    }
    return __low2float(lacc) + __high2float(lacc);
}

// ---------------------------------------------------------------------------
// Kernel A: one thread per PREDICATE node. __launch_bounds__(256, 8) caps the
// allocator at 64 VGPRs (the only knob that works — r17/r19 lessons); live
// ~55 regs fits -> spill-free at 8-waves/EU-capable allocation.
// ---------------------------------------------------------------------------
__global__ __launch_bounds__(256, 8)
void pred_build_kernel(
    const float* __restrict__ b_att,
    const int* __restrict__ pred_ids, const int* __restrict__ var_ids,
    const int* __restrict__ op_ids,
    const float* __restrict__ ws, float* __restrict__ out)
{
    const int i = blockIdx.x*256 + threadIdx.x;     // pred node
    const __half* wsh = (const __half*)ws;
    const float* lgf = ws + F_LG;
    const int j = i >> 1, side = i & 1;

    const int p = pred_ids[i];
    int v[5];
#pragma unroll
    for (int s = 0; s < 5; ++s) v[s] = var_ids[i*5 + s];

    const float e0 = __expf(lgf[p]);
    float den = e0;
    __half2 ek2[5];
#pragma unroll
    for (int s = 0; s < 5; ++s) {
        const float e = __expf(lgf[VOCABSZ + v[s]]);
        den += e;
        ek2[s] = __float2half2_rn(e);
    }
    const float inv = 1.0f / den;

    const uint4* tq = (const uint4*)wsh;
    const __half2* wattg = (const __half2*)(wsh + H_WATT);

    __half2 h2[28];
    const float l = build_node(p, v, __float2half2_rn(e0), ek2,
                               __float2half2_rn(inv), tq, wattg, h2);
    const float wgt = __expf(b_att[0] + l);

    // write h segment: bytes [side*100 .. side*100+100) of out row j
    char* rowb = (char*)out + (size_t)j*OUTROW_B;
    uint* dst = (uint*)(rowb + side*100);
#pragma unroll
    for (int k = 0; k < 25; ++k) { uint u; __builtin_memcpy(&u, &h2[k], 4); dst[k] = u; }

    __half* rowh = (__half*)rowb;
    if (side == 0) {
        rowh[100] = __float2half(wgt);                       // w0
    } else {
        rowh[101] = __float2half(wgt);                       // w2
        const int op = op_ids[j];
        rowh[102] = __float2half(__expf(lgf[2*VOCABSZ + op])); // w1
        rowh[103] = __float2half((float)op);                 // op (<100, exact)
        uint* pz = (uint*)(rowb + 208);                      // halves 104..115 = 0
#pragma unroll
        for (int k = 0; k < 6; ++k) pz[k] = 0u;
    }
}

// ---------------------------------------------------------------------------
// Kernel B: GEMM chain (r19 structure, functionally verified). 128-thr
// (2-wave) blocks, zero barriers, wave-private 3.7KB slab.
// __launch_bounds__(128, 8) caps the allocator at 64 VGPRs: without h-state
// the live set (~40-50) fits -> spill-free 64-reg schedule -> up to 8
// waves/EU (r19 lesson: uncapped, the allocator chose a 200-reg luxury
// schedule and occupancy collapsed to 11%).
// ---------------------------------------------------------------------------
__global__ __launch_bounds__(128, 8)
void fused_kernel(
    const float* __restrict__ b_un, const float* __restrict__ b_univ,
    const float* __restrict__ b_fin,
    const float* __restrict__ ws, float* __restrict__ out)
{
    __shared__ __align__(16) char ldsraw[LDS_BYTES];
    const __half* wsh = (const __half*)ws;
    const int tid = threadIdx.x;
    const int w = tid >> 6, l = tid & 63;
    const int lr = l & 15, q = l >> 4;
    const int jwb = blockIdx.x*128 + w*64;      // this wave's node base

    char* slab = ldsraw + w*LB_WAVE;            // [16][232B]

    const __half2* TOg = (const __half2*)(wsh + H_TO);
    const char* Wcg = (const char*)(wsh + H_WC);    // 232B rows, global L2
    const char* Wug = (const char*)(wsh + H_WU);    // 136B rows
    const char* Wvg = (const char*)(wsh + H_WV);
    const char* Wfg = (const char*)(wsh + H_WF);

    for (int c = 0; c < 4; ++c) {
        // ---- cooperative load of 16 H rows (58 uints each) into slab ----
        {
            const char* gsrc = (const char*)out + (size_t)(jwb + c*16)*OUTROW_B;
#pragma unroll
            for (int it = 0; it < 15; ++it) {
                const int f = it*64 + l;
                if (f < 928) {
                    const int row = f / 58, k = f - row*58;
                    const uint u = *(const uint*)(gsrc + (size_t)row*OUTROW_B + k*4);
                    *(uint*)(slab + row*232 + k*4) = u;
                }
            }
        }

        // ---- GEMM1: lin2[16x64] = H[16x116(100)] @ Wcat ----
        f32x4 C1[4];
#pragma unroll
        for (int nt = 0; nt < 4; ++nt) C1[nt] = (f32x4){0.f, 0.f, 0.f, 0.f};
#pragma unroll
        for (int kk = 0; kk < 7; ++kk) {
            f16x4 a = *(const f16x4*)(slab + lr*232 + kk*32 + q*8);
#pragma unroll
            for (int nt = 0; nt < 4; ++nt) {
                f16x4 b = *(const f16x4*)(Wcg + (nt*16 + lr)*232 + kk*32 + q*8);
                C1[nt] = __builtin_amdgcn_mfma_f32_16x16x16f16(a, b, C1[nt], 0, 0, 0);
            }
        }
        // epilogue: h_bin = relu(lin2 + Tb[op]) + (w0*hA + w2*hB + w1*oe[op])/den
        {
            const __half* sh = (const __half*)slab;
#pragma unroll
            for (int r = 0; r < 4; ++r) {
                const int row = q*4 + r;
                const float w0v = __half2float(sh[row*116 + 100]);
                const float w2v = __half2float(sh[row*116 + 101]);
                const float w1v = __half2float(sh[row*116 + 102]);
                const int   opn = (int)__half2float(sh[row*116 + 103]);
                const float inv2 = 1.0f / (w0v + w1v + w2v);
#pragma unroll
                for (int nt = 0; nt < 4; ++nt) {
                    const int d = nt*16 + lr;
                    float vv = 0.0f;
                    if (d < LDIM) {
                        const float2 to = __half22float2(TOg[opn*LDIM + d]);   // {Tb, oe}
                        const float hAv = __half2float(sh[row*116 + d]);
                        const float hBv = __half2float(sh[row*116 + 50 + d]);
                        vv = fmaxf(C1[nt][r] + to.x, 0.0f)
                           + (w0v*hAv + w2v*hBv + w1v*to.y)*inv2;
                    }
                    C1[nt][r] = vv;
                }
            }
            __half* shw = (__half*)slab;
#pragma unroll
            for (int nt = 0; nt < 4; ++nt)
#pragma unroll
                for (int r = 0; r < 4; ++r)
                    shw[(q*4 + r)*116 + nt*16 + lr] = __float2half(C1[nt][r]);
        }

        // ---- GEMM2: h_un = relu(h_bin @ W_un + b_un) ----
        {
            f32x4 C2[4];
#pragma unroll
            for (int nt = 0; nt < 4; ++nt) C2[nt] = (f32x4){0.f, 0.f, 0.f, 0.f};
#pragma unroll
            for (int kk = 0; kk < 4; ++kk) {
                f16x4 a = *(const f16x4*)(slab + lr*232 + kk*32 + q*8);
#pragma unroll
                for (int nt = 0; nt < 4; ++nt) {
                    f16x4 b = *(const f16x4*)(Wug + (nt*16 + lr)*136 + kk*32 + q*8);
                    C2[nt] = __builtin_amdgcn_mfma_f32_16x16x16f16(a, b, C2[nt], 0, 0, 0);
                }
            }
            __half* shw = (__half*)slab;
#pragma unroll
            for (int nt = 0; nt < 4; ++nt) {
                const int d = nt*16 + lr;
                const float bu = (d < LDIM) ? b_un[d] : 0.0f;
#pragma unroll
                for (int r = 0; r < 4; ++r) {
                    const float vv = (d < LDIM) ? fmaxf(C2[nt][r] + bu, 0.0f) : 0.0f;
                    shw[(q*4 + r)*116 + d] = __float2half(vv);
                }
            }
        }

        // ---- GEMM3: h_q = relu(h_un @ W_univ + b_univ) ----
        {
            f32x4 C3[4];
#pragma unroll
            for (int nt = 0; nt < 4; ++nt) C3[nt] = (f32x4){0.f, 0.f, 0.f, 0.f};
#pragma unroll
            for (int kk = 0; kk < 4; ++kk) {
                f16x4 a = *(const f16x4*)(slab + lr*232 + kk*32 + q*8);
#pragma unroll
                for (int nt = 0; nt < 4; ++nt) {
                    f16x4 b = *(const f16x4*)(Wvg + (nt*16 + lr)*136 + kk*32 + q*8);
                    C3[nt] = __builtin_amdgcn_mfma_f32_16x16x16f16(a, b, C3[nt], 0, 0, 0);
                }
            }
            __half* shw = (__half*)slab;
#pragma unroll
            for (int nt = 0; nt < 4; ++nt) {
                const int d = nt*16 + lr;
                const float bv = (d < LDIM) ? b_univ[d] : 0.0f;
#pragma unroll
                for (int r = 0; r < 4; ++r) {
                    const float vv = (d < LDIM) ? fmaxf(C3[nt][r] + bv, 0.0f) : 0.0f;
                    shw[(q*4 + r)*116 + d] = __float2half(vv);
                }
            }
        }

        // ---- GEMM4: out = h_q @ W_fin + b_fin (overwrites the scratch rows) ----
        {
            float* gb = out + (size_t)(jwb + c*16) * ODIM;
            for (int nt = 0; nt < 10; ++nt) {
                f16x4 bf[4];
#pragma unroll
                for (int kk = 0; kk < 4; ++kk)
                    bf[kk] = *(const f16x4*)(Wfg + (nt*16 + lr)*136 + kk*32 + q*8);
                f32x4 c4 = (f32x4){0.f, 0.f, 0.f, 0.f};
#pragma unroll
                for (int kk = 0; kk < 4; ++kk) {
                    f16x4 a = *(const f16x4*)(slab + lr*232 + kk*32 + q*8);
                    c4 = __builtin_amdgcn_mfma_f32_16x16x16f16(a, bf[kk], c4, 0, 0, 0);
                }
                const int o = nt*16 + lr;
                const float bv = (o < ODIM) ? b_fin[o] : 0.0f;
#pragma unroll
                for (int r = 0; r < 4; ++r)
                    *(float*)(slab + (q*4 + r)*232 + 128 + lr*4) = c4[r] + bv;
#pragma unroll
                for (int it = 0; it < 4; ++it) {
                    const int row = it*4 + q;
                    if (o < ODIM)
                        gb[row*ODIM + nt*16 + lr] =
                            *(const float*)(slab + row*232 + 128 + lr*4);
                }
            }
        }
    }
}

// ---------------------------------------------------------------------------
extern "C" void kernel_launch(void* const* d_in, const int* in_sizes, int n_in,
                              void* d_out, int out_size, void* d_ws, size_t ws_size,
                              hipStream_t stream) {
    const float* pe     = (const float*)d_in[0];
    const float* ve     = (const float*)d_in[1];
    const float* oe     = (const float*)d_in[2];
    const float* W_pred = (const float*)d_in[3];
    const float* b_pred = (const float*)d_in[4];
    const float* W_bin  = (const float*)d_in[5];
    const float* b_bin  = (const float*)d_in[6];
    const float* W_un   = (const float*)d_in[7];
    const float* b_un   = (const float*)d_in[8];
    const float* W_univ = (const float*)d_in[9];
    const float* b_univ = (const float*)d_in[10];
    const float* W_att  = (const float*)d_in[11];
    const float* b_att  = (const float*)d_in[12];
    const float* W_fin  = (const float*)d_in[13];
    const float* b_fin  = (const float*)d_in[14];
    const int* pred_ids = (const int*)d_in[15];
    const int* var_ids  = (const int*)d_in[16];
    const int* op_ids   = (const int*)d_in[17];
    float* out = (float*)d_out;
    float* ws  = (float*)d_ws;

    precompute_kernel<<<181, 256, 0, stream>>>(pe, ve, oe, W_pred, b_pred,
                                               W_bin, b_bin, W_un, W_univ, W_fin,
                                               W_att, b_att, ws);
    pred_build_kernel<<<(2*MBIN)/256, 256, 0, stream>>>(b_att, pred_ids, var_ids,
                                                        op_ids, ws, out);
    fused_kernel<<<MBIN/128, 128, 0, stream>>>(b_un, b_univ, b_fin, ws, out);
}

// Round 21
// 758.657 us; speedup vs baseline: 1.1362x; 1.1362x over previous
//
#include <hip/hip_runtime.h>
#include <hip/hip_fp16.h>

#define LDIM 50
#define MBIN 262144
#define ODIM 155
#define VOCABSZ 100

typedef _Float16 f16x4 __attribute__((ext_vector_type(4)));
typedef _Float16 f16x2 __attribute__((ext_vector_type(2)));
typedef float    f32x4 __attribute__((ext_vector_type(4)));

// packed fp16 relu: v_pk_max_f16 with 0 (ROCm 7.2 header lacks __hmax2)
static __device__ __forceinline__ __half2 relu2(__half2 a) {
    f16x2 av; __builtin_memcpy(&av, &a, sizeof(av));
    const f16x2 zv = {(_Float16)0.0f, (_Float16)0.0f};
    f16x2 r = __builtin_elementwise_max(av, zv);
    __half2 out; __builtin_memcpy(&out, &r, sizeof(out));
    return out;
}

// ---- workspace half-offsets (from (__half*)ws) ----
#define H_TBL  0       // 800*56 halves padded gather tables (T|pe|ve)
#define H_TO   44800   // [100][50] half2 pairs {Tb, oe}
#define H_WC   54800   // WtCat  [64][116]  (232B rows, rows k>=100 ZERO)
#define H_WU   62224   // W_unT  [64][68]   (136B rows)
#define H_WV   66576   // W_univT[64][68]
#define H_WF   70928   // W_finT [160][68]  (ends 81808)
#define H_WATT 81808   // 28 half2 padded W_att
#define F_LG   40960   // float-offset: 300 attention logits fp32

// H scratch row layout (first 232B of each out row j, written by pred_build):
//   halves [0..50)=hA, [50..100)=hB, [100]=w0, [101]=w2, [102]=w1,
//   [103]=(half)op, [104..116)=0.  GEMM1's Wcat rows 100..103 are zero, so
//   the scalar pad contributes nothing to lin2.
#define OUTROW_B 620    // bytes per out row (155 f32)

// ---- kernel B LDS: per-wave slab [16][232B]; 2 waves/block ----
#define LB_WAVE 3712
#define LDS_BYTES (2*LB_WAVE)   // 7424 B

// ---------------------------------------------------------------------------
// Precompute: identical to rounds 18-20 (proven)
// ---------------------------------------------------------------------------
__global__ __launch_bounds__(256) void precompute_kernel(
    const float* __restrict__ pe, const float* __restrict__ ve, const float* __restrict__ oe,
    const float* __restrict__ W_pred, const float* __restrict__ b_pred,
    const float* __restrict__ W_bin, const float* __restrict__ b_bin,
    const float* __restrict__ W_un, const float* __restrict__ W_univ,
    const float* __restrict__ W_fin,
    const float* __restrict__ W_att, const float* __restrict__ b_att,
    float* __restrict__ ws)
{
    __half* wsh = (__half*)ws;
    const int bid = blockIdx.x, tid = threadIdx.x;
    if (bid < 150) {
        const int row = bid*4 + (tid >> 6);
        const int t = tid & 63;
        const int s = row / VOCABSZ, v = row % VOCABSZ;
        if (t < 56) {
            float acc = 0.0f;
            if (t < 50) {
                acc = (s == 0) ? b_pred[t] : 0.0f;
                const float* E = (s == 0) ? pe : ve;
#pragma unroll
                for (int e = 0; e < 50; ++e)
                    acc += E[v*50 + e] * W_pred[(s*50 + e)*50 + t];
            }
            wsh[H_TBL + row*56 + t] = __float2half_rn(acc);
        }
    } else if (bid < 152) {
        const int which = bid - 150;
        const float* E = which ? ve : pe;
        const int base = H_TBL + (600 + which*100) * 56;
        for (int idx = tid; idx < 5600; idx += 256) {
            const int r = idx / 56, c = idx % 56;
            wsh[base + idx] = __float2half_rn((c < 50) ? E[r*50 + c] : 0.0f);
        }
    } else if (bid < 177) {
        const int v = (bid - 152)*4 + (tid >> 6);
        const int t = tid & 63;
        if (t < 50) {
            float acc = b_bin[t];
#pragma unroll
            for (int e = 0; e < 50; ++e)
                acc += oe[v*50 + e] * W_bin[(50 + e)*50 + t];
            wsh[H_TO + (v*50 + t)*2]     = __float2half_rn(acc);
            wsh[H_TO + (v*50 + t)*2 + 1] = __float2half_rn(oe[v*50 + t]);
        }
    } else if (bid == 177) {
        const int n = tid & 63, kc = tid >> 6;
        for (int k = kc*29; k < kc*29 + 29; ++k) {
            float val = 0.0f;
            if (n < 50) {
                if (k < 50)       val = W_bin[k*50 + n];
                else if (k < 100) val = W_bin[(100 + k - 50)*50 + n];
            }
            wsh[H_WC + n*116 + k] = __float2half_rn(val);
        }
    } else if (bid == 178) {
        const int n = tid & 63;
        const int half = tid >> 7;
        const int kc = (tid >> 6) & 1;
        const float* W = half ? W_univ : W_un;
        const int base = half ? H_WV : H_WU;
        for (int k = kc*34; k < kc*34 + 34; ++k) {
            float val = (n < 50 && k < 50) ? W[k*50 + n] : 0.0f;
            wsh[base + n*68 + k] = __float2half_rn(val);
        }
    } else if (bid == 179) {
        for (int idx = tid; idx < 10880; idx += 256) {
            const int n = idx % 160, k = idx / 160;
            float val = (n < ODIM && k < 50) ? W_fin[k*ODIM + n] : 0.0f;
            wsh[H_WF + n*68 + k] = __float2half_rn(val);
        }
    } else {                                // bid == 180: logits fp32 + watt half2
        for (int g = tid; g < 300; g += 256) {
            const int which = g / VOCABSZ, v = g % VOCABSZ;
            const float* E = (which == 0) ? pe : ((which == 1) ? ve : oe);
            float acc = b_att[0];
#pragma unroll
            for (int e = 0; e < 50; ++e)
                acc += E[v*50 + e] * W_att[e];
            ws[F_LG + g] = acc;
        }
        if (tid < 28) {
            const float x = (2*tid < 50)   ? W_att[2*tid]   : 0.0f;
            const float y = (2*tid+1 < 50) ? W_att[2*tid+1] : 0.0f;
            ((__half2*)(wsh + H_WATT))[tid] = __floats2half2_rn(x, y);
        }
    }
}

// ---------------------------------------------------------------------------
// Build one predicate node — packed fp16 from GLOBAL tables (r15 proven)
// ---------------------------------------------------------------------------
__device__ __forceinline__ float build_node(
    int p, const int* __restrict__ v, __half2 e02, const __half2* __restrict__ ek2,
    __half2 invs, const uint4* __restrict__ tq, const __half2* __restrict__ wattl,
    __half2* __restrict__ h2out)
{
    const __half2 z2 = __floats2half2_rn(0.0f, 0.0f);
    __half2 lacc = z2;
#pragma unroll
    for (int g = 0; g < 7; ++g) {
        uint4 ul = tq[p*7 + g];
        uint4 up = tq[(600 + p)*7 + g];
        __half2 lin[4], num[4];
#pragma unroll
        for (int k = 0; k < 4; ++k) {
            lin[k] = ((const __half2*)&ul)[k];
            num[k] = __hmul2(e02, ((const __half2*)&up)[k]);
        }
#pragma unroll
        for (int s = 0; s < 5; ++s) {
            uint4 ua = tq[((s+1)*VOCABSZ + v[s])*7 + g];
            uint4 uv = tq[(700 + v[s])*7 + g];
#pragma unroll
            for (int k = 0; k < 4; ++k) {
                lin[k] = __hadd2(lin[k], ((const __half2*)&ua)[k]);
                num[k] = __hfma2(ek2[s], ((const __half2*)&uv)[k], num[k]);
            }
        }
#pragma unroll
        for (int k = 0; k < 4; ++k) {
            const __half2 h = __hfma2(num[k], invs, relu2(lin[k]));
            h2out[g*4 + k] = h;
            lacc = __hfma2(h, wattl[g*4 + k], lacc);
        }
    }
    return __low2float(lacc) + __high2float(lacc);
}

// ---------------------------------------------------------------------------
// Kernel A: one thread per PREDICATE node. __launch_bounds__(256, 3):
// empirical allocator law (r16/r17/r20): chosen VGPR ~= 256/min_waves.
// w=3 -> ~85 regs; live ~72 (h2[28] + pipelined uint4s) fits -> spill-free
// at 3+ waves/EU. (r20's w=8 -> 32 regs spilled everything.)
// ---------------------------------------------------------------------------
__global__ __launch_bounds__(256, 3)
void pred_build_kernel(
    const float* __restrict__ b_att,
    const int* __restrict__ pred_ids, const int* __restrict__ var_ids,
    const int* __restrict__ op_ids,
    const float* __restrict__ ws, float* __restrict__ out)
{
    const int i = blockIdx.x*256 + threadIdx.x;     // pred node
    const __half* wsh = (const __half*)ws;
    const float* lgf = ws + F_LG;
    const int j = i >> 1, side = i & 1;

    const int p = pred_ids[i];
    int v[5];
#pragma unroll
    for (int s = 0; s < 5; ++s) v[s] = var_ids[i*5 + s];

    const float e0 = __expf(lgf[p]);
    float den = e0;
    __half2 ek2[5];
#pragma unroll
    for (int s = 0; s < 5; ++s) {
        const float e = __expf(lgf[VOCABSZ + v[s]]);
        den += e;
        ek2[s] = __float2half2_rn(e);
    }
    const float inv = 1.0f / den;

    const uint4* tq = (const uint4*)wsh;
    const __half2* wattg = (const __half2*)(wsh + H_WATT);

    __half2 h2[28];
    const float l = build_node(p, v, __float2half2_rn(e0), ek2,
                               __float2half2_rn(inv), tq, wattg, h2);
    const float wgt = __expf(b_att[0] + l);

    // write h segment: bytes [side*100 .. side*100+100) of out row j
    char* rowb = (char*)out + (size_t)j*OUTROW_B;
    uint* dst = (uint*)(rowb + side*100);
#pragma unroll
    for (int k = 0; k < 25; ++k) { uint u; __builtin_memcpy(&u, &h2[k], 4); dst[k] = u; }

    __half* rowh = (__half*)rowb;
    if (side == 0) {
        rowh[100] = __float2half(wgt);                       // w0
    } else {
        rowh[101] = __float2half(wgt);                       // w2
        const int op = op_ids[j];
        rowh[102] = __float2half(__expf(lgf[2*VOCABSZ + op])); // w1
        rowh[103] = __float2half((float)op);                 // op (<100, exact)
        uint* pz = (uint*)(rowb + 208);                      // halves 104..115 = 0
#pragma unroll
        for (int k = 0; k < 6; ++k) pz[k] = 0u;
    }
}

// ---------------------------------------------------------------------------
// Kernel B: GEMM chain (r19/r20 structure, functionally verified). 128-thr
// (2-wave) blocks, zero barriers, wave-private 3.7KB slab.
// __launch_bounds__(128, 3): ~85-reg budget per the 256/w law; live ~50-65
// (no h-state) fits spill-free under EITHER interpretation of the law,
// with 3-6 waves/EU residency. (r19 uncapped -> 200-reg luxury, 11% occ;
// r20 w=8 -> 32 regs, total spill.)
// ---------------------------------------------------------------------------
__global__ __launch_bounds__(128, 3)
void fused_kernel(
    const float* __restrict__ b_un, const float* __restrict__ b_univ,
    const float* __restrict__ b_fin,
    const float* __restrict__ ws, float* __restrict__ out)
{
    __shared__ __align__(16) char ldsraw[LDS_BYTES];
    const __half* wsh = (const __half*)ws;
    const int tid = threadIdx.x;
    const int w = tid >> 6, l = tid & 63;
    const int lr = l & 15, q = l >> 4;
    const int jwb = blockIdx.x*128 + w*64;      // this wave's node base

    char* slab = ldsraw + w*LB_WAVE;            // [16][232B]

    const __half2* TOg = (const __half2*)(wsh + H_TO);
    const char* Wcg = (const char*)(wsh + H_WC);    // 232B rows, global L2
    const char* Wug = (const char*)(wsh + H_WU);    // 136B rows
    const char* Wvg = (const char*)(wsh + H_WV);
    const char* Wfg = (const char*)(wsh + H_WF);

    for (int c = 0; c < 4; ++c) {
        // ---- cooperative load of 16 H rows (58 uints each) into slab ----
        {
            const char* gsrc = (const char*)out + (size_t)(jwb + c*16)*OUTROW_B;
#pragma unroll
            for (int it = 0; it < 15; ++it) {
                const int f = it*64 + l;
                if (f < 928) {
                    const int row = f / 58, k = f - row*58;
                    const uint u = *(const uint*)(gsrc + (size_t)row*OUTROW_B + k*4);
                    *(uint*)(slab + row*232 + k*4) = u;
                }
            }
        }

        // ---- GEMM1: lin2[16x64] = H[16x116(100)] @ Wcat ----
        f32x4 C1[4];
#pragma unroll
        for (int nt = 0; nt < 4; ++nt) C1[nt] = (f32x4){0.f, 0.f, 0.f, 0.f};
#pragma unroll
        for (int kk = 0; kk < 7; ++kk) {
            f16x4 a = *(const f16x4*)(slab + lr*232 + kk*32 + q*8);
#pragma unroll
            for (int nt = 0; nt < 4; ++nt) {
                f16x4 b = *(const f16x4*)(Wcg + (nt*16 + lr)*232 + kk*32 + q*8);
                C1[nt] = __builtin_amdgcn_mfma_f32_16x16x16f16(a, b, C1[nt], 0, 0, 0);
            }
        }
        // epilogue: h_bin = relu(lin2 + Tb[op]) + (w0*hA + w2*hB + w1*oe[op])/den
        {
            const __half* sh = (const __half*)slab;
#pragma unroll
            for (int r = 0; r < 4; ++r) {
                const int row = q*4 + r;
                const float w0v = __half2float(sh[row*116 + 100]);
                const float w2v = __half2float(sh[row*116 + 101]);
                const float w1v = __half2float(sh[row*116 + 102]);
                const int   opn = (int)__half2float(sh[row*116 + 103]);
                const float inv2 = 1.0f / (w0v + w1v + w2v);
#pragma unroll
                for (int nt = 0; nt < 4; ++nt) {
                    const int d = nt*16 + lr;
                    float vv = 0.0f;
                    if (d < LDIM) {
                        const float2 to = __half22float2(TOg[opn*LDIM + d]);   // {Tb, oe}
                        const float hAv = __half2float(sh[row*116 + d]);
                        const float hBv = __half2float(sh[row*116 + 50 + d]);
                        vv = fmaxf(C1[nt][r] + to.x, 0.0f)
                           + (w0v*hAv + w2v*hBv + w1v*to.y)*inv2;
                    }
                    C1[nt][r] = vv;
                }
            }
            __half* shw = (__half*)slab;
#pragma unroll
            for (int nt = 0; nt < 4; ++nt)
#pragma unroll
                for (int r = 0; r < 4; ++r)
                    shw[(q*4 + r)*116 + nt*16 + lr] = __float2half(C1[nt][r]);
        }

        // ---- GEMM2: h_un = relu(h_bin @ W_un + b_un) ----
        {
            f32x4 C2[4];
#pragma unroll
            for (int nt = 0; nt < 4; ++nt) C2[nt] = (f32x4){0.f, 0.f, 0.f, 0.f};
#pragma unroll
            for (int kk = 0; kk < 4; ++kk) {
                f16x4 a = *(const f16x4*)(slab + lr*232 + kk*32 + q*8);
#pragma unroll
                for (int nt = 0; nt < 4; ++nt) {
                    f16x4 b = *(const f16x4*)(Wug + (nt*16 + lr)*136 + kk*32 + q*8);
                    C2[nt] = __builtin_amdgcn_mfma_f32_16x16x16f16(a, b, C2[nt], 0, 0, 0);
                }
            }
            __half* shw = (__half*)slab;
#pragma unroll
            for (int nt = 0; nt < 4; ++nt) {
                const int d = nt*16 + lr;
                const float bu = (d < LDIM) ? b_un[d] : 0.0f;
#pragma unroll
                for (int r = 0; r < 4; ++r) {
                    const float vv = (d < LDIM) ? fmaxf(C2[nt][r] + bu, 0.0f) : 0.0f;
                    shw[(q*4 + r)*116 + d] = __float2half(vv);
                }
            }
        }

        // ---- GEMM3: h_q = relu(h_un @ W_univ + b_univ) ----
        {
            f32x4 C3[4];
#pragma unroll
            for (int nt = 0; nt < 4; ++nt) C3[nt] = (f32x4){0.f, 0.f, 0.f, 0.f};
#pragma unroll
            for (int kk = 0; kk < 4; ++kk) {
                f16x4 a = *(const f16x4*)(slab + lr*232 + kk*32 + q*8);
#pragma unroll
                for (int nt = 0; nt < 4; ++nt) {
                    f16x4 b = *(const f16x4*)(Wvg + (nt*16 + lr)*136 + kk*32 + q*8);
                    C3[nt] = __builtin_amdgcn_mfma_f32_16x16x16f16(a, b, C3[nt], 0, 0, 0);
                }
            }
            __half* shw = (__half*)slab;
#pragma unroll
            for (int nt = 0; nt < 4; ++nt) {
                const int d = nt*16 + lr;
                const float bv = (d < LDIM) ? b_univ[d] : 0.0f;
#pragma unroll
                for (int r = 0; r < 4; ++r) {
                    const float vv = (d < LDIM) ? fmaxf(C3[nt][r] + bv, 0.0f) : 0.0f;
                    shw[(q*4 + r)*116 + d] = __float2half(vv);
                }
            }
        }

        // ---- GEMM4: out = h_q @ W_fin + b_fin (overwrites the scratch rows) ----
        {
            float* gb = out + (size_t)(jwb + c*16) * ODIM;
            for (int nt = 0; nt < 10; ++nt) {
                f16x4 bf[4];
#pragma unroll
                for (int kk = 0; kk < 4; ++kk)
                    bf[kk] = *(const f16x4*)(Wfg + (nt*16 + lr)*136 + kk*32 + q*8);
                f32x4 c4 = (f32x4){0.f, 0.f, 0.f, 0.f};
#pragma unroll
                for (int kk = 0; kk < 4; ++kk) {
                    f16x4 a = *(const f16x4*)(slab + lr*232 + kk*32 + q*8);
                    c4 = __builtin_amdgcn_mfma_f32_16x16x16f16(a, bf[kk], c4, 0, 0, 0);
                }
                const int o = nt*16 + lr;
                const float bv = (o < ODIM) ? b_fin[o] : 0.0f;
#pragma unroll
                for (int r = 0; r < 4; ++r)
                    *(float*)(slab + (q*4 + r)*232 + 128 + lr*4) = c4[r] + bv;
#pragma unroll
                for (int it = 0; it < 4; ++it) {
                    const int row = it*4 + q;
                    if (o < ODIM)
                        gb[row*ODIM + nt*16 + lr] =
                            *(const float*)(slab + row*232 + 128 + lr*4);
                }
            }
        }
    }
}

// ---------------------------------------------------------------------------
extern "C" void kernel_launch(void* const* d_in, const int* in_sizes, int n_in,
                              void* d_out, int out_size, void* d_ws, size_t ws_size,
                              hipStream_t stream) {
    const float* pe     = (const float*)d_in[0];
    const float* ve     = (const float*)d_in[1];
    const float* oe     = (const float*)d_in[2];
    const float* W_pred = (const float*)d_in[3];
    const float* b_pred = (const float*)d_in[4];
    const float* W_bin  = (const float*)d_in[5];
    const float* b_bin  = (const float*)d_in[6];
    const float* W_un   = (const float*)d_in[7];
    const float* b_un   = (const float*)d_in[8];
    const float* W_univ = (const float*)d_in[9];
    const float* b_univ = (const float*)d_in[10];
    const float* W_att  = (const float*)d_in[11];
    const float* b_att  = (const float*)d_in[12];
    const float* W_fin  = (const float*)d_in[13];
    const float* b_fin  = (const float*)d_in[14];
    const int* pred_ids = (const int*)d_in[15];
    const int* var_ids  = (const int*)d_in[16];
    const int* op_ids   = (const int*)d_in[17];
    float* out = (float*)d_out;
    float* ws  = (float*)d_ws;

    precompute_kernel<<<181, 256, 0, stream>>>(pe, ve, oe, W_pred, b_pred,
                                               W_bin, b_bin, W_un, W_univ, W_fin,
                                               W_att, b_att, ws);
    pred_build_kernel<<<(2*MBIN)/256, 256, 0, stream>>>(b_att, pred_ids, var_ids,
                                                        op_ids, ws, out);
    fused_kernel<<<MBIN/128, 128, 0, stream>>>(b_un, b_univ, b_fin, ws, out);
}

// Round 22
// 313.699 us; speedup vs baseline: 2.7477x; 2.4184x over previous
//
#include <hip/hip_runtime.h>
#include <hip/hip_fp16.h>

#define LDIM 50
#define MBIN 262144
#define ODIM 155
#define VOCABSZ 100

typedef _Float16 f16x4 __attribute__((ext_vector_type(4)));
typedef _Float16 f16x2 __attribute__((ext_vector_type(2)));
typedef float    f32x4 __attribute__((ext_vector_type(4)));

// packed fp16 relu: v_pk_max_f16 with 0 (ROCm 7.2 header lacks __hmax2)
static __device__ __forceinline__ __half2 relu2(__half2 a) {
    f16x2 av; __builtin_memcpy(&av, &a, sizeof(av));
    const f16x2 zv = {(_Float16)0.0f, (_Float16)0.0f};
    f16x2 r = __builtin_elementwise_max(av, zv);
    __half2 out; __builtin_memcpy(&out, &r, sizeof(out));
    return out;
}

// ---- workspace half-offsets (from (__half*)ws) — r14/r15 layout ----
#define H_TBL  0       // 800*56 halves padded gather tables (T|pe|ve)
#define H_TO   44800   // [100][50] half2 pairs {Tb, oe}
#define H_WC   54800   // WtCat  [64][116]
#define H_WU   62224   // W_unT  [64][68]
#define H_WV   66576   // W_univT[64][68]
#define H_WF   70928   // W_finT [160][68]
#define F_LG   40960   // float-offset: 300 attention logits fp32

// ---- LDS byte offsets: TOTAL 72640 B (r15-proven spill-free config) ----
// per-wave chunk slab: [16][116] fp16 (232B rows); sww overlays bytes 128..196
#define LB_SLAB 0        // 8 waves x 3712 = 29696
#define LB_WC   29696    // 14848
#define LB_WU   44544    // 8704
#define LB_WV   53248    // 8704
#define LB_OP   61952    // 512 int
#define LB_W0   64000
#define LB_W2   66048
#define LB_W1   68096
#define LB_BU   70144
#define LB_BV   70400
#define LB_BF   70656
#define LB_LG   71296
#define LB_WATT 72512
#define LDS_BYTES 72640

// ---------------------------------------------------------------------------
// Precompute: identical to round 14/15 (proven, ~13 us)
// ---------------------------------------------------------------------------
__global__ __launch_bounds__(256) void precompute_kernel(
    const float* __restrict__ pe, const float* __restrict__ ve, const float* __restrict__ oe,
    const float* __restrict__ W_pred, const float* __restrict__ b_pred,
    const float* __restrict__ W_bin, const float* __restrict__ b_bin,
    const float* __restrict__ W_un, const float* __restrict__ W_univ,
    const float* __restrict__ W_fin,
    const float* __restrict__ W_att, const float* __restrict__ b_att,
    float* __restrict__ ws)
{
    __half* wsh = (__half*)ws;
    const int bid = blockIdx.x, tid = threadIdx.x;
    if (bid < 150) {
        const int row = bid*4 + (tid >> 6);
        const int t = tid & 63;
        const int s = row / VOCABSZ, v = row % VOCABSZ;
        if (t < 56) {
            float acc = 0.0f;
            if (t < 50) {
                acc = (s == 0) ? b_pred[t] : 0.0f;
                const float* E = (s == 0) ? pe : ve;
#pragma unroll
                for (int e = 0; e < 50; ++e)
                    acc += E[v*50 + e] * W_pred[(s*50 + e)*50 + t];
            }
            wsh[H_TBL + row*56 + t] = __float2half_rn(acc);
        }
    } else if (bid < 152) {
        const int which = bid - 150;
        const float* E = which ? ve : pe;
        const int base = H_TBL + (600 + which*100) * 56;
        for (int idx = tid; idx < 5600; idx += 256) {
            const int r = idx / 56, c = idx % 56;
            wsh[base + idx] = __float2half_rn((c < 50) ? E[r*50 + c] : 0.0f);
        }
    } else if (bid < 177) {
        const int v = (bid - 152)*4 + (tid >> 6);
        const int t = tid & 63;
        if (t < 50) {
            float acc = b_bin[t];
#pragma unroll
            for (int e = 0; e < 50; ++e)
                acc += oe[v*50 + e] * W_bin[(50 + e)*50 + t];
            wsh[H_TO + (v*50 + t)*2]     = __float2half_rn(acc);
            wsh[H_TO + (v*50 + t)*2 + 1] = __float2half_rn(oe[v*50 + t]);
        }
    } else if (bid == 177) {
        const int n = tid & 63, kc = tid >> 6;
        for (int k = kc*29; k < kc*29 + 29; ++k) {
            float val = 0.0f;
            if (n < 50) {
                if (k < 50)       val = W_bin[k*50 + n];
                else if (k < 100) val = W_bin[(100 + k - 50)*50 + n];
            }
            wsh[H_WC + n*116 + k] = __float2half_rn(val);
        }
    } else if (bid == 178) {
        const int n = tid & 63;
        const int half = tid >> 7;
        const int kc = (tid >> 6) & 1;
        const float* W = half ? W_univ : W_un;
        const int base = half ? H_WV : H_WU;
        for (int k = kc*34; k < kc*34 + 34; ++k) {
            float val = (n < 50 && k < 50) ? W[k*50 + n] : 0.0f;
            wsh[base + n*68 + k] = __float2half_rn(val);
        }
    } else if (bid == 179) {
        for (int idx = tid; idx < 10880; idx += 256) {
            const int n = idx % 160, k = idx / 160;
            float val = (n < ODIM && k < 50) ? W_fin[k*ODIM + n] : 0.0f;
            wsh[H_WF + n*68 + k] = __float2half_rn(val);
        }
    } else {
        for (int g = tid; g < 300; g += 256) {
            const int which = g / VOCABSZ, v = g % VOCABSZ;
            const float* E = (which == 0) ? pe : ((which == 1) ? ve : oe);
            float acc = b_att[0];
#pragma unroll
            for (int e = 0; e < 50; ++e)
                acc += E[v*50 + e] * W_att[e];
            ws[F_LG + g] = acc;
        }
    }
}

// ---------------------------------------------------------------------------
// Build one predicate node — packed fp16 (r14 proven math), tables read
// from GLOBAL (L2-resident 90KB; 12-deep load ILP hides ~200cyc latency).
// ---------------------------------------------------------------------------
__device__ __forceinline__ float build_node(
    int p, const int* __restrict__ v, __half2 e02, const __half2* __restrict__ ek2,
    __half2 invs, const uint4* __restrict__ tq, const __half2* __restrict__ wattl,
    __half2* __restrict__ h2out)
{
    const __half2 z2 = __floats2half2_rn(0.0f, 0.0f);
    __half2 lacc = z2;
#pragma unroll
    for (int g = 0; g < 7; ++g) {
        uint4 ul = tq[p*7 + g];                   // T pred row (b_pred folded)
        uint4 up = tq[(600 + p)*7 + g];           // pe row
        __half2 lin[4], num[4];
#pragma unroll
        for (int k = 0; k < 4; ++k) {
            lin[k] = ((const __half2*)&ul)[k];
            num[k] = __hmul2(e02, ((const __half2*)&up)[k]);
        }
#pragma unroll
        for (int s = 0; s < 5; ++s) {
            uint4 ua = tq[((s+1)*VOCABSZ + v[s])*7 + g];   // T arg-slot row
            uint4 uv = tq[(700 + v[s])*7 + g];             // ve row
#pragma unroll
            for (int k = 0; k < 4; ++k) {
                lin[k] = __hadd2(lin[k], ((const __half2*)&ua)[k]);
                num[k] = __hfma2(ek2[s], ((const __half2*)&uv)[k], num[k]);
            }
        }
#pragma unroll
        for (int k = 0; k < 4; ++k) {
            const __half2 h = __hfma2(num[k], invs, relu2(lin[k]));
            h2out[g*4 + k] = h;
            lacc = __hfma2(h, wattl[g*4 + k], lacc);
        }
    }
    return __low2float(lacc) + __high2float(lacc);
}

// ---------------------------------------------------------------------------
// Fused kernel (r15 structure — best measured: fused 133us, spill-free):
// 512 thr, wave w owns 64 nodes; NO block barriers after P0. Gather from
// global L2; wave-private slabs; GEMM1..4 on MFMA.
// __launch_bounds__(512, 1): rounds 16-21 established that the 2nd arg is
// the only working allocator knob (chosen VGPR ~= 256/min_waves). Here the
// block is 8 waves on one CU (2 waves/SIMD mandatory) so a 256-reg ceiling
// CANNOT reduce occupancy — it only grants scheduling headroom vs r15's 128.
// Worst case the allocator stays at 128 = exact r15 reproduction.
// ---------------------------------------------------------------------------
__global__ __launch_bounds__(512, 1)
void fused_kernel(
    const float* __restrict__ W_att, const float* __restrict__ b_att,
    const float* __restrict__ b_un, const float* __restrict__ b_univ,
    const float* __restrict__ b_fin,
    const int* __restrict__ pred_ids, const int* __restrict__ var_ids,
    const int* __restrict__ op_ids,
    const float* __restrict__ ws, float* __restrict__ out)
{
    __shared__ __align__(16) char ldsraw[LDS_BYTES];
    const __half* wsh = (const __half*)ws;
    const int tid = threadIdx.x;
    const int w = tid >> 6, l = tid & 63;
    const int lr = l & 15, q = l >> 4;
    const int jbase = blockIdx.x * 512;

    int*   opl = (int*)(ldsraw + LB_OP);
    float* w0l = (float*)(ldsraw + LB_W0);
    float* w2l = (float*)(ldsraw + LB_W2);
    float* w1l = (float*)(ldsraw + LB_W1);
    float* bul = (float*)(ldsraw + LB_BU);
    float* bvl = (float*)(ldsraw + LB_BV);
    float* bfl = (float*)(ldsraw + LB_BF);
    float* lgl = (float*)(ldsraw + LB_LG);

    // ---- P0: stage Wc/Wu/Wv + scalars (tables stay in global/L2) ----
    {
        const uint4* sc = (const uint4*)(wsh + H_WC);       // 928 uint4
        uint4* dc = (uint4*)(ldsraw + LB_WC);
        for (int i = tid; i < 928; i += 512) dc[i] = sc[i];
        const uint4* su = (const uint4*)(wsh + H_WU);       // 544
        uint4* du = (uint4*)(ldsraw + LB_WU);
        for (int i = tid; i < 544; i += 512) du[i] = su[i];
        const uint4* sv = (const uint4*)(wsh + H_WV);       // 544
        uint4* dv = (uint4*)(ldsraw + LB_WV);
        for (int i = tid; i < 544; i += 512) dv[i] = sv[i];
        if (tid < 300) lgl[tid] = ws[F_LG + tid];
        if (tid < LDIM) { bul[tid] = b_un[tid]; bvl[tid] = b_univ[tid]; }
        if (tid < ODIM) bfl[tid] = b_fin[tid];
        if (tid >= 256 && tid < 284) {
            const int i = tid - 256;
            const float x = (2*i < 50)   ? W_att[2*i]   : 0.0f;
            const float y = (2*i+1 < 50) ? W_att[2*i+1] : 0.0f;
            ((__half2*)(ldsraw + LB_WATT))[i] = __floats2half2_rn(x, y);
        }
    }
    __syncthreads();                                        // B0 (the only barrier)

    // ---- P1: packed-fp16 gather-build from GLOBAL tables ----
    const int j = jbase + tid;
    int vA[5], vB[5];
    const int pA = pred_ids[2*j], pB = pred_ids[2*j+1];
#pragma unroll
    for (int s = 0; s < 5; ++s) { vA[s] = var_ids[(2*j)*5 + s]; vB[s] = var_ids[(2*j+1)*5 + s]; }
    const int op = op_ids[j];

    float ekA[5], ekB[5];
    const float e0A = __expf(lgl[pA]);
    const float e0B = __expf(lgl[pB]);
    float denA = e0A, denB = e0B;
#pragma unroll
    for (int s = 0; s < 5; ++s) {
        ekA[s] = __expf(lgl[VOCABSZ + vA[s]]); denA += ekA[s];
        ekB[s] = __expf(lgl[VOCABSZ + vB[s]]); denB += ekB[s];
    }
    const float invA = 1.0f / denA, invB = 1.0f / denB;
    const float batt = b_att[0];

    __half2 ek2A[5], ek2B[5];
#pragma unroll
    for (int s = 0; s < 5; ++s) {
        ek2A[s] = __float2half2_rn(ekA[s]);
        ek2B[s] = __float2half2_rn(ekB[s]);
    }

    const uint4* tq = (const uint4*)wsh;                    // padded tables, global
    const __half2* wattl = (const __half2*)(ldsraw + LB_WATT);

    __half2 hA2[28], hB2[28];
    const float w0 = __expf(batt + build_node(pA, vA, __float2half2_rn(e0A), ek2A,
                                              __float2half2_rn(invA), tq, wattl, hA2));
    const float w2 = __expf(batt + build_node(pB, vB, __float2half2_rn(e0B), ek2B,
                                              __float2half2_rn(invB), tq, wattl, hB2));
    const float w1 = __expf(lgl[2*VOCABSZ + op]);
    const float inv2 = 1.0f / (w0 + w1 + w2);

    // publish per-node scalars (consumed only by own wave -> no barrier)
    opl[tid] = op;
    w0l[tid] = w0*inv2; w2l[tid] = w2*inv2; w1l[tid] = w1*inv2;

    char* slab = ldsraw + LB_SLAB + w*3712;                 // [16][116] fp16, 232B rows
    const __half2* TOg = (const __half2*)(wsh + H_TO);
    const _Float16* Wcp = (const _Float16*)(ldsraw + LB_WC);
    const _Float16* Wup = (const _Float16*)(ldsraw + LB_WU);
    const _Float16* Wvp = (const _Float16*)(ldsraw + LB_WV);
    const _Float16* Wfg = (const _Float16*)(wsh + H_WF);    // global, L2-hot

    for (int c = 0; c < 4; ++c) {
        // ---- owner lanes write chunk H rows [hA|hB|zeros] ----
        if ((l >> 4) == c) {
            uint* dst = (uint*)(slab + (l & 15)*232);
#pragma unroll
            for (int i = 0; i < 25; ++i) { uint u; __builtin_memcpy(&u, &hA2[i], 4); dst[i] = u; }
#pragma unroll
            for (int i = 0; i < 25; ++i) { uint u; __builtin_memcpy(&u, &hB2[i], 4); dst[25+i] = u; }
#pragma unroll
            for (int i = 50; i < 58; ++i) dst[i] = 0u;
        }

        // ---- GEMM1: lin2[16x64] = H[16x116(100)] @ Wcat ----
        f32x4 C1[4];
#pragma unroll
        for (int nt = 0; nt < 4; ++nt) C1[nt] = (f32x4){0.f, 0.f, 0.f, 0.f};
#pragma unroll
        for (int kk = 0; kk < 7; ++kk) {
            f16x4 a = *(const f16x4*)(slab + lr*232 + kk*32 + q*8);
#pragma unroll
            for (int nt = 0; nt < 4; ++nt) {
                f16x4 b = *(const f16x4*)((const char*)Wcp + (nt*16 + lr)*232 + kk*32 + q*8);
                C1[nt] = __builtin_amdgcn_mfma_f32_16x16x16f16(a, b, C1[nt], 0, 0, 0);
            }
        }
        // epilogue: h_bin = relu(lin2 + Tb[op]) + w0i*hA + w2i*hB + w1i*oe[op]
        {
            const __half* sh = (const __half*)slab;
            const int cb = c*16;
#pragma unroll
            for (int nt = 0; nt < 4; ++nt) {
                const int d = nt*16 + lr;
#pragma unroll
                for (int r = 0; r < 4; ++r) {
                    const int nw = w*64 + cb + q*4 + r;
                    float v = 0.0f;
                    if (d < LDIM) {
                        const int opn = opl[nw];
                        const float2 to = __half22float2(TOg[opn*LDIM + d]);   // {Tb, oe}
                        const float hAv = __half2float(sh[(q*4 + r)*116 + d]);
                        const float hBv = __half2float(sh[(q*4 + r)*116 + 50 + d]);
                        v = fmaxf(C1[nt][r] + to.x, 0.0f)
                          + w0l[nw]*hAv + w2l[nw]*hBv + w1l[nw]*to.y;
                    }
                    C1[nt][r] = v;
                }
            }
            __half* shw = (__half*)slab;
#pragma unroll
            for (int nt = 0; nt < 4; ++nt)
#pragma unroll
                for (int r = 0; r < 4; ++r)
                    shw[(q*4 + r)*116 + nt*16 + lr] = __float2half(C1[nt][r]);
        }

        // ---- GEMM2: h_un = relu(h_bin @ W_un + b_un) ----
        {
            f32x4 C2[4];
#pragma unroll
            for (int nt = 0; nt < 4; ++nt) C2[nt] = (f32x4){0.f, 0.f, 0.f, 0.f};
#pragma unroll
            for (int kk = 0; kk < 4; ++kk) {
                f16x4 a = *(const f16x4*)(slab + lr*232 + kk*32 + q*8);
#pragma unroll
                for (int nt = 0; nt < 4; ++nt) {
                    f16x4 b = *(const f16x4*)((const char*)Wup + (nt*16 + lr)*136 + kk*32 + q*8);
                    C2[nt] = __builtin_amdgcn_mfma_f32_16x16x16f16(a, b, C2[nt], 0, 0, 0);
                }
            }
            __half* shw = (__half*)slab;
#pragma unroll
            for (int nt = 0; nt < 4; ++nt) {
                const int d = nt*16 + lr;
#pragma unroll
                for (int r = 0; r < 4; ++r) {
                    const float v = (d < LDIM) ? fmaxf(C2[nt][r] + bul[d], 0.0f) : 0.0f;
                    shw[(q*4 + r)*116 + d] = __float2half(v);
                }
            }
        }

        // ---- GEMM3: h_q = relu(h_un @ W_univ + b_univ) ----
        {
            f32x4 C3[4];
#pragma unroll
            for (int nt = 0; nt < 4; ++nt) C3[nt] = (f32x4){0.f, 0.f, 0.f, 0.f};
#pragma unroll
            for (int kk = 0; kk < 4; ++kk) {
                f16x4 a = *(const f16x4*)(slab + lr*232 + kk*32 + q*8);
#pragma unroll
                for (int nt = 0; nt < 4; ++nt) {
                    f16x4 b = *(const f16x4*)((const char*)Wvp + (nt*16 + lr)*136 + kk*32 + q*8);
                    C3[nt] = __builtin_amdgcn_mfma_f32_16x16x16f16(a, b, C3[nt], 0, 0, 0);
                }
            }
            __half* shw = (__half*)slab;
#pragma unroll
            for (int nt = 0; nt < 4; ++nt) {
                const int d = nt*16 + lr;
#pragma unroll
                for (int r = 0; r < 4; ++r) {
                    const float v = (d < LDIM) ? fmaxf(C3[nt][r] + bvl[d], 0.0f) : 0.0f;
                    shw[(q*4 + r)*116 + d] = __float2half(v);
                }
            }
        }

        // ---- GEMM4: out = h_q @ W_fin + b_fin (B from global L2) ----
        // sww transpose buffer embedded in slab bytes [row*232+128 .. +196)
        {
            float* gb = out + (size_t)(jbase + w*64 + c*16) * ODIM;
            for (int nt = 0; nt < 10; ++nt) {
                f16x4 bf[4];
#pragma unroll
                for (int kk = 0; kk < 4; ++kk)
                    bf[kk] = *(const f16x4*)((const char*)Wfg + (nt*16 + lr)*136 + kk*32 + q*8);
                f32x4 c4 = (f32x4){0.f, 0.f, 0.f, 0.f};
#pragma unroll
                for (int kk = 0; kk < 4; ++kk) {
                    f16x4 a = *(const f16x4*)(slab + lr*232 + kk*32 + q*8);
                    c4 = __builtin_amdgcn_mfma_f32_16x16x16f16(a, bf[kk], c4, 0, 0, 0);
                }
                const int o = nt*16 + lr;
                const float bv = (o < ODIM) ? bfl[o] : 0.0f;
#pragma unroll
                for (int r = 0; r < 4; ++r)
                    *(float*)(slab + (q*4 + r)*232 + 128 + lr*4) = c4[r] + bv;
#pragma unroll
                for (int it = 0; it < 4; ++it) {
                    const int row = it*4 + q;
                    if (o < ODIM)
                        gb[row*ODIM + nt*16 + lr] =
                            *(const float*)(slab + row*232 + 128 + lr*4);
                }
            }
        }
    }
}

// ---------------------------------------------------------------------------
extern "C" void kernel_launch(void* const* d_in, const int* in_sizes, int n_in,
                              void* d_out, int out_size, void* d_ws, size_t ws_size,
                              hipStream_t stream) {
    const float* pe     = (const float*)d_in[0];
    const float* ve     = (const float*)d_in[1];
    const float* oe     = (const float*)d_in[2];
    const float* W_pred = (const float*)d_in[3];
    const float* b_pred = (const float*)d_in[4];
    const float* W_bin  = (const float*)d_in[5];
    const float* b_bin  = (const float*)d_in[6];
    const float* W_un   = (const float*)d_in[7];
    const float* b_un   = (const float*)d_in[8];
    const float* W_univ = (const float*)d_in[9];
    const float* b_univ = (const float*)d_in[10];
    const float* W_att  = (const float*)d_in[11];
    const float* b_att  = (const float*)d_in[12];
    const float* W_fin  = (const float*)d_in[13];
    const float* b_fin  = (const float*)d_in[14];
    const int* pred_ids = (const int*)d_in[15];
    const int* var_ids  = (const int*)d_in[16];
    const int* op_ids   = (const int*)d_in[17];
    float* out = (float*)d_out;
    float* ws  = (float*)d_ws;

    precompute_kernel<<<181, 256, 0, stream>>>(pe, ve, oe, W_pred, b_pred,
                                               W_bin, b_bin, W_un, W_univ, W_fin,
                                               W_att, b_att, ws);
    fused_kernel<<<MBIN/512, 512, 0, stream>>>(W_att, b_att, b_un, b_univ, b_fin,
                                               pred_ids, var_ids, op_ids, ws, out);
}

// Round 23
// 313.047 us; speedup vs baseline: 2.7534x; 1.0021x over previous
//
#include <hip/hip_runtime.h>
#include <hip/hip_fp16.h>

#define LDIM 50
#define MBIN 262144
#define ODIM 155
#define VOCABSZ 100

typedef _Float16 f16x4 __attribute__((ext_vector_type(4)));
typedef _Float16 f16x2 __attribute__((ext_vector_type(2)));
typedef float    f32x4 __attribute__((ext_vector_type(4)));

// packed fp16 relu: v_pk_max_f16 with 0 (ROCm 7.2 header lacks __hmax2)
static __device__ __forceinline__ __half2 relu2(__half2 a) {
    f16x2 av; __builtin_memcpy(&av, &a, sizeof(av));
    const f16x2 zv = {(_Float16)0.0f, (_Float16)0.0f};
    f16x2 r = __builtin_elementwise_max(av, zv);
    __half2 out; __builtin_memcpy(&out, &r, sizeof(out));
    return out;
}

// ---- workspace half-offsets (from (__half*)ws) — r14/r15 layout ----
#define H_TBL  0       // 800*56 halves padded gather tables (T|pe|ve)
#define H_TO   44800   // [100][50] half2 pairs {Tb, oe}
#define H_WC   54800   // WtCat  [64][116]
#define H_WU   62224   // W_unT  [64][68]
#define H_WV   66576   // W_univT[64][68]
#define H_WF   70928   // W_finT [160][68]
#define F_LG   40960   // float-offset: 300 attention logits fp32

// ---- LDS byte offsets: TOTAL 134400 B ----
// r15-22 proved 1 block/CU is immovable at 512-thr, so LDS frugality buys
// nothing: use the free 87KB to stage TO (40KB) + W_finT (21.8KB), converting
// the epilogue's scattered global TO gather (64 loads/thr, ~200cyc) and
// GEMM4's 160 global B-loads/thr into LDS reads.
#define LB_SLAB 0        // 8 waves x 3712 = 29696
#define LB_WC   29696    // 14848
#define LB_WU   44544    // 8704
#define LB_WV   53248    // 8704
#define LB_WF   61952    // 21760  (W_finT [160][68])
#define LB_TO   83712    // 40000  ({Tb,oe} half2 pairs [100][50])
#define LB_OP   123712   // 512 int
#define LB_W0   125760
#define LB_W2   127808
#define LB_W1   129856
#define LB_BU   131904   // 200 B
#define LB_BV   132160   // 200 B
#define LB_BF   132416   // 620 B
#define LB_LG   133056   // 1200 B
#define LB_WATT 134272   // 112 B
#define LDS_BYTES 134400

// ---------------------------------------------------------------------------
// Precompute: identical to round 14/15/22 (proven, ~13 us)
// ---------------------------------------------------------------------------
__global__ __launch_bounds__(256) void precompute_kernel(
    const float* __restrict__ pe, const float* __restrict__ ve, const float* __restrict__ oe,
    const float* __restrict__ W_pred, const float* __restrict__ b_pred,
    const float* __restrict__ W_bin, const float* __restrict__ b_bin,
    const float* __restrict__ W_un, const float* __restrict__ W_univ,
    const float* __restrict__ W_fin,
    const float* __restrict__ W_att, const float* __restrict__ b_att,
    float* __restrict__ ws)
{
    __half* wsh = (__half*)ws;
    const int bid = blockIdx.x, tid = threadIdx.x;
    if (bid < 150) {
        const int row = bid*4 + (tid >> 6);
        const int t = tid & 63;
        const int s = row / VOCABSZ, v = row % VOCABSZ;
        if (t < 56) {
            float acc = 0.0f;
            if (t < 50) {
                acc = (s == 0) ? b_pred[t] : 0.0f;
                const float* E = (s == 0) ? pe : ve;
#pragma unroll
                for (int e = 0; e < 50; ++e)
                    acc += E[v*50 + e] * W_pred[(s*50 + e)*50 + t];
            }
            wsh[H_TBL + row*56 + t] = __float2half_rn(acc);
        }
    } else if (bid < 152) {
        const int which = bid - 150;
        const float* E = which ? ve : pe;
        const int base = H_TBL + (600 + which*100) * 56;
        for (int idx = tid; idx < 5600; idx += 256) {
            const int r = idx / 56, c = idx % 56;
            wsh[base + idx] = __float2half_rn((c < 50) ? E[r*50 + c] : 0.0f);
        }
    } else if (bid < 177) {
        const int v = (bid - 152)*4 + (tid >> 6);
        const int t = tid & 63;
        if (t < 50) {
            float acc = b_bin[t];
#pragma unroll
            for (int e = 0; e < 50; ++e)
                acc += oe[v*50 + e] * W_bin[(50 + e)*50 + t];
            wsh[H_TO + (v*50 + t)*2]     = __float2half_rn(acc);
            wsh[H_TO + (v*50 + t)*2 + 1] = __float2half_rn(oe[v*50 + t]);
        }
    } else if (bid == 177) {
        const int n = tid & 63, kc = tid >> 6;
        for (int k = kc*29; k < kc*29 + 29; ++k) {
            float val = 0.0f;
            if (n < 50) {
                if (k < 50)       val = W_bin[k*50 + n];
                else if (k < 100) val = W_bin[(100 + k - 50)*50 + n];
            }
            wsh[H_WC + n*116 + k] = __float2half_rn(val);
        }
    } else if (bid == 178) {
        const int n = tid & 63;
        const int half = tid >> 7;
        const int kc = (tid >> 6) & 1;
        const float* W = half ? W_univ : W_un;
        const int base = half ? H_WV : H_WU;
        for (int k = kc*34; k < kc*34 + 34; ++k) {
            float val = (n < 50 && k < 50) ? W[k*50 + n] : 0.0f;
            wsh[base + n*68 + k] = __float2half_rn(val);
        }
    } else if (bid == 179) {
        for (int idx = tid; idx < 10880; idx += 256) {
            const int n = idx % 160, k = idx / 160;
            float val = (n < ODIM && k < 50) ? W_fin[k*ODIM + n] : 0.0f;
            wsh[H_WF + n*68 + k] = __float2half_rn(val);
        }
    } else {
        for (int g = tid; g < 300; g += 256) {
            const int which = g / VOCABSZ, v = g % VOCABSZ;
            const float* E = (which == 0) ? pe : ((which == 1) ? ve : oe);
            float acc = b_att[0];
#pragma unroll
            for (int e = 0; e < 50; ++e)
                acc += E[v*50 + e] * W_att[e];
            ws[F_LG + g] = acc;
        }
    }
}

// ---------------------------------------------------------------------------
// Build one predicate node — packed fp16 (r14 proven math), tables read
// from GLOBAL (L2-resident 90KB; 12-deep load ILP hides ~200cyc latency).
// ---------------------------------------------------------------------------
__device__ __forceinline__ float build_node(
    int p, const int* __restrict__ v, __half2 e02, const __half2* __restrict__ ek2,
    __half2 invs, const uint4* __restrict__ tq, const __half2* __restrict__ wattl,
    __half2* __restrict__ h2out)
{
    const __half2 z2 = __floats2half2_rn(0.0f, 0.0f);
    __half2 lacc = z2;
#pragma unroll
    for (int g = 0; g < 7; ++g) {
        uint4 ul = tq[p*7 + g];                   // T pred row (b_pred folded)
        uint4 up = tq[(600 + p)*7 + g];           // pe row
        __half2 lin[4], num[4];
#pragma unroll
        for (int k = 0; k < 4; ++k) {
            lin[k] = ((const __half2*)&ul)[k];
            num[k] = __hmul2(e02, ((const __half2*)&up)[k]);
        }
#pragma unroll
        for (int s = 0; s < 5; ++s) {
            uint4 ua = tq[((s+1)*VOCABSZ + v[s])*7 + g];   // T arg-slot row
            uint4 uv = tq[(700 + v[s])*7 + g];             // ve row
#pragma unroll
            for (int k = 0; k < 4; ++k) {
                lin[k] = __hadd2(lin[k], ((const __half2*)&ua)[k]);
                num[k] = __hfma2(ek2[s], ((const __half2*)&uv)[k], num[k]);
            }
        }
#pragma unroll
        for (int k = 0; k < 4; ++k) {
            const __half2 h = __hfma2(num[k], invs, relu2(lin[k]));
            h2out[g*4 + k] = h;
            lacc = __hfma2(h, wattl[g*4 + k], lacc);
        }
    }
    return __low2float(lacc) + __high2float(lacc);
}

// ---------------------------------------------------------------------------
// Fused kernel (r15/r22 structure + TO/W_finT staged in LDS):
// 512 thr, wave w owns 64 nodes; NO block barriers after P0. Gather from
// global L2; wave-private slabs; GEMM1..4 on MFMA with ALL weights + the
// TO epilogue table now in LDS.
// ---------------------------------------------------------------------------
__global__ __launch_bounds__(512)
void fused_kernel(
    const float* __restrict__ W_att, const float* __restrict__ b_att,
    const float* __restrict__ b_un, const float* __restrict__ b_univ,
    const float* __restrict__ b_fin,
    const int* __restrict__ pred_ids, const int* __restrict__ var_ids,
    const int* __restrict__ op_ids,
    const float* __restrict__ ws, float* __restrict__ out)
{
    __shared__ __align__(16) char ldsraw[LDS_BYTES];
    const __half* wsh = (const __half*)ws;
    const int tid = threadIdx.x;
    const int w = tid >> 6, l = tid & 63;
    const int lr = l & 15, q = l >> 4;
    const int jbase = blockIdx.x * 512;

    int*   opl = (int*)(ldsraw + LB_OP);
    float* w0l = (float*)(ldsraw + LB_W0);
    float* w2l = (float*)(ldsraw + LB_W2);
    float* w1l = (float*)(ldsraw + LB_W1);
    float* bul = (float*)(ldsraw + LB_BU);
    float* bvl = (float*)(ldsraw + LB_BV);
    float* bfl = (float*)(ldsraw + LB_BF);
    float* lgl = (float*)(ldsraw + LB_LG);

    // ---- P0: stage Wc/Wu/Wv/Wf/TO + scalars (gather tables stay in L2) ----
    {
        const uint4* sc = (const uint4*)(wsh + H_WC);       // 928 uint4
        uint4* dc = (uint4*)(ldsraw + LB_WC);
        for (int i = tid; i < 928; i += 512) dc[i] = sc[i];
        const uint4* su = (const uint4*)(wsh + H_WU);       // 544
        uint4* du = (uint4*)(ldsraw + LB_WU);
        for (int i = tid; i < 544; i += 512) du[i] = su[i];
        const uint4* sv = (const uint4*)(wsh + H_WV);       // 544
        uint4* dv = (uint4*)(ldsraw + LB_WV);
        for (int i = tid; i < 544; i += 512) dv[i] = sv[i];
        const uint4* sf = (const uint4*)(wsh + H_WF);       // 1360
        uint4* df = (uint4*)(ldsraw + LB_WF);
        for (int i = tid; i < 1360; i += 512) df[i] = sf[i];
        const uint4* st = (const uint4*)(wsh + H_TO);       // 2500
        uint4* dt = (uint4*)(ldsraw + LB_TO);
        for (int i = tid; i < 2500; i += 512) dt[i] = st[i];
        if (tid < 300) lgl[tid] = ws[F_LG + tid];
        if (tid < LDIM) { bul[tid] = b_un[tid]; bvl[tid] = b_univ[tid]; }
        if (tid < ODIM) bfl[tid] = b_fin[tid];
        if (tid >= 256 && tid < 284) {
            const int i = tid - 256;
            const float x = (2*i < 50)   ? W_att[2*i]   : 0.0f;
            const float y = (2*i+1 < 50) ? W_att[2*i+1] : 0.0f;
            ((__half2*)(ldsraw + LB_WATT))[i] = __floats2half2_rn(x, y);
        }
    }
    __syncthreads();                                        // B0 (the only barrier)

    // ---- P1: packed-fp16 gather-build from GLOBAL tables ----
    const int j = jbase + tid;
    int vA[5], vB[5];
    const int pA = pred_ids[2*j], pB = pred_ids[2*j+1];
#pragma unroll
    for (int s = 0; s < 5; ++s) { vA[s] = var_ids[(2*j)*5 + s]; vB[s] = var_ids[(2*j+1)*5 + s]; }
    const int op = op_ids[j];

    float ekA[5], ekB[5];
    const float e0A = __expf(lgl[pA]);
    const float e0B = __expf(lgl[pB]);
    float denA = e0A, denB = e0B;
#pragma unroll
    for (int s = 0; s < 5; ++s) {
        ekA[s] = __expf(lgl[VOCABSZ + vA[s]]); denA += ekA[s];
        ekB[s] = __expf(lgl[VOCABSZ + vB[s]]); denB += ekB[s];
    }
    const float invA = 1.0f / denA, invB = 1.0f / denB;
    const float batt = b_att[0];

    __half2 ek2A[5], ek2B[5];
#pragma unroll
    for (int s = 0; s < 5; ++s) {
        ek2A[s] = __float2half2_rn(ekA[s]);
        ek2B[s] = __float2half2_rn(ekB[s]);
    }

    const uint4* tq = (const uint4*)wsh;                    // padded tables, global
    const __half2* wattl = (const __half2*)(ldsraw + LB_WATT);

    __half2 hA2[28], hB2[28];
    const float w0 = __expf(batt + build_node(pA, vA, __float2half2_rn(e0A), ek2A,
                                              __float2half2_rn(invA), tq, wattl, hA2));
    const float w2 = __expf(batt + build_node(pB, vB, __float2half2_rn(e0B), ek2B,
                                              __float2half2_rn(invB), tq, wattl, hB2));
    const float w1 = __expf(lgl[2*VOCABSZ + op]);
    const float inv2 = 1.0f / (w0 + w1 + w2);

    // publish per-node scalars (consumed only by own wave -> no barrier)
    opl[tid] = op;
    w0l[tid] = w0*inv2; w2l[tid] = w2*inv2; w1l[tid] = w1*inv2;

    char* slab = ldsraw + LB_SLAB + w*3712;                 // [16][116] fp16, 232B rows
    const __half2* TOl = (const __half2*)(ldsraw + LB_TO);  // LDS now
    const _Float16* Wcp = (const _Float16*)(ldsraw + LB_WC);
    const _Float16* Wup = (const _Float16*)(ldsraw + LB_WU);
    const _Float16* Wvp = (const _Float16*)(ldsraw + LB_WV);
    const _Float16* Wfp = (const _Float16*)(ldsraw + LB_WF); // LDS now

    for (int c = 0; c < 4; ++c) {
        // ---- owner lanes write chunk H rows [hA|hB|zeros] ----
        if ((l >> 4) == c) {
            uint* dst = (uint*)(slab + (l & 15)*232);
#pragma unroll
            for (int i = 0; i < 25; ++i) { uint u; __builtin_memcpy(&u, &hA2[i], 4); dst[i] = u; }
#pragma unroll
            for (int i = 0; i < 25; ++i) { uint u; __builtin_memcpy(&u, &hB2[i], 4); dst[25+i] = u; }
#pragma unroll
            for (int i = 50; i < 58; ++i) dst[i] = 0u;
        }

        // ---- GEMM1: lin2[16x64] = H[16x116(100)] @ Wcat ----
        f32x4 C1[4];
#pragma unroll
        for (int nt = 0; nt < 4; ++nt) C1[nt] = (f32x4){0.f, 0.f, 0.f, 0.f};
#pragma unroll
        for (int kk = 0; kk < 7; ++kk) {
            f16x4 a = *(const f16x4*)(slab + lr*232 + kk*32 + q*8);
#pragma unroll
            for (int nt = 0; nt < 4; ++nt) {
                f16x4 b = *(const f16x4*)((const char*)Wcp + (nt*16 + lr)*232 + kk*32 + q*8);
                C1[nt] = __builtin_amdgcn_mfma_f32_16x16x16f16(a, b, C1[nt], 0, 0, 0);
            }
        }
        // epilogue: h_bin = relu(lin2 + Tb[op]) + w0i*hA + w2i*hB + w1i*oe[op]
        {
            const __half* sh = (const __half*)slab;
            const int cb = c*16;
#pragma unroll
            for (int nt = 0; nt < 4; ++nt) {
                const int d = nt*16 + lr;
#pragma unroll
                for (int r = 0; r < 4; ++r) {
                    const int nw = w*64 + cb + q*4 + r;
                    float v = 0.0f;
                    if (d < LDIM) {
                        const int opn = opl[nw];
                        const float2 to = __half22float2(TOl[opn*LDIM + d]);   // {Tb, oe} from LDS
                        const float hAv = __half2float(sh[(q*4 + r)*116 + d]);
                        const float hBv = __half2float(sh[(q*4 + r)*116 + 50 + d]);
                        v = fmaxf(C1[nt][r] + to.x, 0.0f)
                          + w0l[nw]*hAv + w2l[nw]*hBv + w1l[nw]*to.y;
                    }
                    C1[nt][r] = v;
                }
            }
            __half* shw = (__half*)slab;
#pragma unroll
            for (int nt = 0; nt < 4; ++nt)
#pragma unroll
                for (int r = 0; r < 4; ++r)
                    shw[(q*4 + r)*116 + nt*16 + lr] = __float2half(C1[nt][r]);
        }

        // ---- GEMM2: h_un = relu(h_bin @ W_un + b_un) ----
        {
            f32x4 C2[4];
#pragma unroll
            for (int nt = 0; nt < 4; ++nt) C2[nt] = (f32x4){0.f, 0.f, 0.f, 0.f};
#pragma unroll
            for (int kk = 0; kk < 4; ++kk) {
                f16x4 a = *(const f16x4*)(slab + lr*232 + kk*32 + q*8);
#pragma unroll
                for (int nt = 0; nt < 4; ++nt) {
                    f16x4 b = *(const f16x4*)((const char*)Wup + (nt*16 + lr)*136 + kk*32 + q*8);
                    C2[nt] = __builtin_amdgcn_mfma_f32_16x16x16f16(a, b, C2[nt], 0, 0, 0);
                }
            }
            __half* shw = (__half*)slab;
#pragma unroll
            for (int nt = 0; nt < 4; ++nt) {
                const int d = nt*16 + lr;
#pragma unroll
                for (int r = 0; r < 4; ++r) {
                    const float v = (d < LDIM) ? fmaxf(C2[nt][r] + bul[d], 0.0f) : 0.0f;
                    shw[(q*4 + r)*116 + d] = __float2half(v);
                }
            }
        }

        // ---- GEMM3: h_q = relu(h_un @ W_univ + b_univ) ----
        {
            f32x4 C3[4];
#pragma unroll
            for (int nt = 0; nt < 4; ++nt) C3[nt] = (f32x4){0.f, 0.f, 0.f, 0.f};
#pragma unroll
            for (int kk = 0; kk < 4; ++kk) {
                f16x4 a = *(const f16x4*)(slab + lr*232 + kk*32 + q*8);
#pragma unroll
                for (int nt = 0; nt < 4; ++nt) {
                    f16x4 b = *(const f16x4*)((const char*)Wvp + (nt*16 + lr)*136 + kk*32 + q*8);
                    C3[nt] = __builtin_amdgcn_mfma_f32_16x16x16f16(a, b, C3[nt], 0, 0, 0);
                }
            }
            __half* shw = (__half*)slab;
#pragma unroll
            for (int nt = 0; nt < 4; ++nt) {
                const int d = nt*16 + lr;
#pragma unroll
                for (int r = 0; r < 4; ++r) {
                    const float v = (d < LDIM) ? fmaxf(C3[nt][r] + bvl[d], 0.0f) : 0.0f;
                    shw[(q*4 + r)*116 + d] = __float2half(v);
                }
            }
        }

        // ---- GEMM4: out = h_q @ W_fin + b_fin (B from LDS) ----
        // sww transpose buffer embedded in slab bytes [row*232+128 .. +196)
        {
            float* gb = out + (size_t)(jbase + w*64 + c*16) * ODIM;
            for (int nt = 0; nt < 10; ++nt) {
                f16x4 bf[4];
#pragma unroll
                for (int kk = 0; kk < 4; ++kk)
                    bf[kk] = *(const f16x4*)((const char*)Wfp + (nt*16 + lr)*136 + kk*32 + q*8);
                f32x4 c4 = (f32x4){0.f, 0.f, 0.f, 0.f};
#pragma unroll
                for (int kk = 0; kk < 4; ++kk) {
                    f16x4 a = *(const f16x4*)(slab + lr*232 + kk*32 + q*8);
                    c4 = __builtin_amdgcn_mfma_f32_16x16x16f16(a, bf[kk], c4, 0, 0, 0);
                }
                const int o = nt*16 + lr;
                const float bv = (o < ODIM) ? bfl[o] : 0.0f;
#pragma unroll
                for (int r = 0; r < 4; ++r)
                    *(float*)(slab + (q*4 + r)*232 + 128 + lr*4) = c4[r] + bv;
#pragma unroll
                for (int it = 0; it < 4; ++it) {
                    const int row = it*4 + q;
                    if (o < ODIM)
                        gb[row*ODIM + nt*16 + lr] =
                            *(const float*)(slab + row*232 + 128 + lr*4);
                }
            }
        }
    }
}

// ---------------------------------------------------------------------------
extern "C" void kernel_launch(void* const* d_in, const int* in_sizes, int n_in,
                              void* d_out, int out_size, void* d_ws, size_t ws_size,
                              hipStream_t stream) {
    const float* pe     = (const float*)d_in[0];
    const float* ve     = (const float*)d_in[1];
    const float* oe     = (const float*)d_in[2];
    const float* W_pred = (const float*)d_in[3];
    const float* b_pred = (const float*)d_in[4];
    const float* W_bin  = (const float*)d_in[5];
    const float* b_bin  = (const float*)d_in[6];
    const float* W_un   = (const float*)d_in[7];
    const float* b_un   = (const float*)d_in[8];
    const float* W_univ = (const float*)d_in[9];
    const float* b_univ = (const float*)d_in[10];
    const float* W_att  = (const float*)d_in[11];
    const float* b_att  = (const float*)d_in[12];
    const float* W_fin  = (const float*)d_in[13];
    const float* b_fin  = (const float*)d_in[14];
    const int* pred_ids = (const int*)d_in[15];
    const int* var_ids  = (const int*)d_in[16];
    const int* op_ids   = (const int*)d_in[17];
    float* out = (float*)d_out;
    float* ws  = (float*)d_ws;

    precompute_kernel<<<181, 256, 0, stream>>>(pe, ve, oe, W_pred, b_pred,
                                               W_bin, b_bin, W_un, W_univ, W_fin,
                                               W_att, b_att, ws);
    fused_kernel<<<MBIN/512, 512, 0, stream>>>(W_att, b_att, b_un, b_univ, b_fin,
                                               pred_ids, var_ids, op_ids, ws, out);
}